// Round 6
// baseline (1666.795 us; speedup 1.0000x reference)
//
#include <hip/hip_runtime.h>

#define NN 100000
#define EE 600000
#define GG 512
#define SSUB 8
#define LL 3
#define EMB 128
#define EDIM 16
#define NTASK 10
#define TOTSUB 4096
#define BN_EPS 1e-5f

// ---------------- CSR build ----------------
__global__ void k_hist(const int* __restrict__ dstp, int* __restrict__ cnt) {
    int e = blockIdx.x * 256 + threadIdx.x;
    if (e < EE) atomicAdd(&cnt[dstp[e]], 1);
}

__global__ void k_scan1(const int* __restrict__ cnt, int* __restrict__ bsum) {
    __shared__ int sd[256];
    int t = threadIdx.x, b = blockIdx.x;
    int n0 = b * 1024 + t * 4;
    int s = 0;
    for (int i = 0; i < 4; ++i) { int n = n0 + i; if (n < NN) s += cnt[n]; }
    sd[t] = s; __syncthreads();
    for (int o = 128; o > 0; o >>= 1) { if (t < o) sd[t] += sd[t + o]; __syncthreads(); }
    if (t == 0) bsum[b] = sd[0];
}

__global__ void k_scan2(const int* __restrict__ bsum, int* __restrict__ bpre, int nb) {
    int run = 0;
    for (int i = 0; i < nb; ++i) { bpre[i] = run; run += bsum[i]; }
}

__global__ void k_scan3(const int* __restrict__ cnt, const int* __restrict__ bpre,
                        int* __restrict__ offs) {
    __shared__ int sd[256];
    int t = threadIdx.x, b = blockIdx.x;
    int n0 = b * 1024 + t * 4;
    int v[4]; int ts = 0;
    for (int i = 0; i < 4; ++i) { int n = n0 + i; v[i] = (n < NN) ? cnt[n] : 0; ts += v[i]; }
    sd[t] = ts; __syncthreads();
    int sum = ts;
    for (int o = 1; o < 256; o <<= 1) {
        int x = (t >= o) ? sd[t - o] : 0;
        __syncthreads();
        sum += x; sd[t] = sum;
        __syncthreads();
    }
    int run = sum - ts + bpre[b];
    for (int i = 0; i < 4; ++i) { int n = n0 + i; if (n < NN) offs[n] = run; run += v[i]; }
}

__global__ void k_fill(const int* __restrict__ srcp, const int* __restrict__ dstp,
                       const int* __restrict__ offs, int* __restrict__ fil,
                       int* __restrict__ elist) {
    int e = blockIdx.x * 256 + threadIdx.x;
    if (e >= EE) return;
    int d = dstp[e];
    int p = atomicAdd(&fil[d], 1);
    elist[offs[d] + p] = srcp[e];
}

// ---------------- edge_attr aggregate (once) ----------------
__global__ void k_ea(const int* __restrict__ dstp, const float* __restrict__ eattr,
                     float* __restrict__ ea) {
    int e = blockIdx.x * 256 + threadIdx.x;
    if (e >= EE) return;
    int d = dstp[e];
#pragma unroll
    for (int j = 0; j < 16; j += 4) {
        float4 v = *(const float4*)&eattr[(size_t)e * 16 + j];
        atomicAdd(&ea[(size_t)d * 16 + j + 0], v.x);
        atomicAdd(&ea[(size_t)d * 16 + j + 1], v.y);
        atomicAdd(&ea[(size_t)d * 16 + j + 2], v.z);
        atomicAdd(&ea[(size_t)d * 16 + j + 3], v.w);
    }
}

// ---------------- per-layer neighbor gather-sum (no atomics) ----------------
__global__ __launch_bounds__(256) void k_agg(const float* __restrict__ h,
                                             const int* __restrict__ offs,
                                             const int* __restrict__ cnt,
                                             const int* __restrict__ elist,
                                             float* __restrict__ agg) {
    int w = (blockIdx.x * 256 + threadIdx.x) >> 6;   // wave per node
    int lane = threadIdx.x & 63;
    if (w >= NN) return;
    int off = offs[w], deg = cnt[w];
    float ax = 0.f, ay = 0.f;
    for (int j = 0; j < deg; ++j) {
        int s = elist[off + j];
        float2 v = *(const float2*)&h[(size_t)s * 128 + lane * 2];
        ax += v.x; ay += v.y;
    }
    float2 o; o.x = ax; o.y = ay;
    *(float2*)&agg[(size_t)w * 128 + lane * 2] = o;
}

// ---------------- fused GEMM: out = b + in0@W0 [+ in1@W1 + in2@W2] ----------------
// 64 rows x 128 cols per block, K chunks of 8 staged in LDS. f32 VALU.
// Optionally accumulates per-column sum/sumsq of the output into statsp[256]
// (BN stats fused into the epilogue; statsp==nullptr skips).
__global__ __launch_bounds__(256) void k_gemm(const float* __restrict__ in0,
                                              const float* __restrict__ in1,
                                              const float* __restrict__ in2,
                                              const float* __restrict__ W0,
                                              const float* __restrict__ W1p,
                                              const float* __restrict__ W2p,
                                              const float* __restrict__ bias,
                                              float* __restrict__ outp, int nseg,
                                              float* __restrict__ statsp) {
    __shared__ union {
        struct { float W[8][128]; float In[64][9]; } s;   // staging (6.3 KB)
        struct { float sum[16][128]; float sq[16][128]; } r; // epilogue reduce (16 KB)
    } sm;
    int t = threadIdx.x;
    int tc = t & 15, tr = t >> 4;
    int rowBase = blockIdx.x * 64;
    float acc[4][8];
#pragma unroll
    for (int i = 0; i < 4; ++i)
#pragma unroll
        for (int j = 0; j < 8; ++j) acc[i][j] = 0.f;

    for (int seg = 0; seg < nseg; ++seg) {
        const float* in = (seg == 0) ? in0 : (seg == 1) ? in1 : in2;
        const float* W  = (seg == 0) ? W0  : (seg == 1) ? W1p : W2p;
        int K = (seg == 2) ? 16 : 128;
        for (int kb = 0; kb < K; kb += 8) {
            {   // stage W chunk: 8x128
                int fo = t * 4, kk = fo >> 7, cc = fo & 127;
                *(float4*)&sm.s.W[kk][cc] = *(const float4*)&W[(size_t)(kb + kk) * 128 + cc];
            }
            {   // stage input chunk: 64 rows x 8 k
                int rr = t >> 2, part = (t & 3) * 2;
                int gr = rowBase + rr;
                float2 v; v.x = 0.f; v.y = 0.f;
                if (gr < NN) v = *(const float2*)&in[(size_t)gr * K + kb + part];
                sm.s.In[rr][part] = v.x; sm.s.In[rr][part + 1] = v.y;
            }
            __syncthreads();
#pragma unroll
            for (int kk = 0; kk < 8; ++kk) {
                float4 wa = *(const float4*)&sm.s.W[kk][tc * 4];
                float4 wb = *(const float4*)&sm.s.W[kk][64 + tc * 4];
#pragma unroll
                for (int i = 0; i < 4; ++i) {
                    float a = sm.s.In[tr * 4 + i][kk];
                    acc[i][0] += a * wa.x; acc[i][1] += a * wa.y;
                    acc[i][2] += a * wa.z; acc[i][3] += a * wa.w;
                    acc[i][4] += a * wb.x; acc[i][5] += a * wb.y;
                    acc[i][6] += a * wb.z; acc[i][7] += a * wb.w;
                }
            }
            __syncthreads();
        }
    }
    float4 ba = *(const float4*)&bias[tc * 4];
    float4 bb = *(const float4*)&bias[64 + tc * 4];
    float ls[8], lq[8];
#pragma unroll
    for (int j = 0; j < 8; ++j) { ls[j] = 0.f; lq[j] = 0.f; }
#pragma unroll
    for (int i = 0; i < 4; ++i) {
        int gr = rowBase + tr * 4 + i;
        if (gr >= NN) continue;
        float o[8];
        o[0] = acc[i][0] + ba.x; o[1] = acc[i][1] + ba.y;
        o[2] = acc[i][2] + ba.z; o[3] = acc[i][3] + ba.w;
        o[4] = acc[i][4] + bb.x; o[5] = acc[i][5] + bb.y;
        o[6] = acc[i][6] + bb.z; o[7] = acc[i][7] + bb.w;
#pragma unroll
        for (int j = 0; j < 8; ++j) { ls[j] += o[j]; lq[j] += o[j] * o[j]; }
        float4 o1, o2;
        o1.x = o[0]; o1.y = o[1]; o1.z = o[2]; o1.w = o[3];
        o2.x = o[4]; o2.y = o[5]; o2.z = o[6]; o2.w = o[7];
        *(float4*)&outp[(size_t)gr * 128 + tc * 4] = o1;
        *(float4*)&outp[(size_t)gr * 128 + 64 + tc * 4] = o2;
    }
    if (statsp) {
        // (last in-loop __syncthreads already separated all reads of sm.s)
#pragma unroll
        for (int j = 0; j < 8; ++j) {
            int col = (j < 4) ? tc * 4 + j : 64 + tc * 4 + (j - 4);
            sm.r.sum[tr][col] = ls[j];
            sm.r.sq[tr][col] = lq[j];
        }
        __syncthreads();
        if (t < 128) {
            float s = 0.f;
#pragma unroll
            for (int r = 0; r < 16; ++r) s += sm.r.sum[r][t];
            atomicAdd(&statsp[t], s);
        } else {
            int c = t - 128;
            float q = 0.f;
#pragma unroll
            for (int r = 0; r < 16; ++r) q += sm.r.sq[r][c];
            atomicAdd(&statsp[128 + c], q);
        }
    }
}

// ---------------- BatchNorm ----------------
__global__ void k_bnfin(const float* __restrict__ stats, const float* __restrict__ gamma,
                        const float* __restrict__ beta, float* __restrict__ ss) {
    int c = threadIdx.x;
    float mu = stats[c] * (1.0f / (float)NN);
    float var = stats[128 + c] * (1.0f / (float)NN) - mu * mu;
    float sc = gamma[c] * rsqrtf(var + BN_EPS);
    ss[c] = sc;
    ss[128 + c] = beta[c] - mu * sc;
}

__global__ void k_bnrelu(const float* __restrict__ h1, const float* __restrict__ ss,
                         float* __restrict__ h) {
    int total = NN * 32;  // float4 count
    for (int i = blockIdx.x * blockDim.x + threadIdx.x; i < total;
         i += gridDim.x * blockDim.x) {
        float4 v = ((const float4*)h1)[i];
        int c = (i * 4) & 127;
        float4 sc = *(const float4*)&ss[c];
        float4 sh = *(const float4*)&ss[128 + c];
        v.x = fmaxf(fmaf(v.x, sc.x, sh.x), 0.f);
        v.y = fmaxf(fmaf(v.y, sc.y, sh.y), 0.f);
        v.z = fmaxf(fmaf(v.z, sc.z, sh.z), 0.f);
        v.w = fmaxf(fmaf(v.w, sc.w, sh.w), 0.f);
        ((float4*)h)[i] = v;
    }
}

// ---------------- pooling (+ fused last-layer BN+ReLU) + final MLP ----------------
__global__ void k_soffs(const int* __restrict__ nsub, int* __restrict__ soffs) {
    int run = 0;
    for (int g = 0; g < GG; ++g) { soffs[g] = run; run += nsub[g]; }
}

__global__ __launch_bounds__(256) void k_pool(const float* __restrict__ h1,
                                              const float* __restrict__ ss,
                                              const int* __restrict__ batch,
                                              const int* __restrict__ subb,
                                              const int* __restrict__ soffs,
                                              float* __restrict__ subsum,
                                              int* __restrict__ scnt) {
    int w = (blockIdx.x * 256 + threadIdx.x) >> 6;
    int lane = threadIdx.x & 63;
    if (w >= NN) return;
    float sc0 = ss[lane * 2],       sc1 = ss[lane * 2 + 1];
    float sh0 = ss[128 + lane * 2], sh1 = ss[128 + lane * 2 + 1];
    int sid = subb[w] + soffs[batch[w]];
    float2 v = *(const float2*)&h1[(size_t)w * 128 + lane * 2];
    v.x = fmaxf(fmaf(v.x, sc0, sh0), 0.f);
    v.y = fmaxf(fmaf(v.y, sc1, sh1), 0.f);
    atomicAdd(&subsum[(size_t)sid * 128 + lane * 2], v.x);
    atomicAdd(&subsum[(size_t)sid * 128 + lane * 2 + 1], v.y);
    if (lane == 0) atomicAdd(&scnt[sid], 1);
}

__global__ __launch_bounds__(256) void k_final(const float* __restrict__ subsum,
                                               const int* __restrict__ scnt,
                                               const int* __restrict__ soffs,
                                               const float* __restrict__ W1,
                                               const float* __restrict__ b1,
                                               const float* __restrict__ W2,
                                               const float* __restrict__ b2,
                                               float* __restrict__ out) {
    __shared__ float hg[128];
    __shared__ float mid[256];
    int g = blockIdx.x, t = threadIdx.x;
    if (t < 128) {
        float s = 0.f;
        int base = soffs[g];
        for (int u = 0; u < SSUB; ++u) {
            int sid = base + u;
            int c = scnt[sid]; if (c < 1) c = 1;
            s += subsum[(size_t)sid * 128 + t] / (float)c;
        }
        hg[t] = s * (1.0f / (float)SSUB);
    }
    __syncthreads();
    {
        float m = b1[t];
        for (int c = 0; c < 128; ++c) m += hg[c] * W1[(size_t)c * 256 + t];
        mid[t] = fmaxf(m, 0.f);
    }
    __syncthreads();
    if (t < NTASK) {
        float o = b2[t];
        for (int j = 0; j < 256; ++j) o += mid[j] * W2[(size_t)j * 10 + t];
        out[(size_t)g * 10 + t] = o;
    }
}

extern "C" void kernel_launch(void* const* d_in, const int* in_sizes, int n_in,
                              void* d_out, int out_size, void* d_ws, size_t ws_size,
                              hipStream_t stream) {
    (void)in_sizes; (void)n_in; (void)out_size; (void)ws_size;
    const float* x     = (const float*)d_in[0];
    const int*   eidx  = (const int*)d_in[1];
    const float* eattr = (const float*)d_in[2];
    const int*   batch = (const int*)d_in[3];
    const int*   subb  = (const int*)d_in[4];
    const int*   nsub  = (const int*)d_in[6];
    const float* encW  = (const float*)d_in[7];
    const float* encB  = (const float*)d_in[8];
    const float* Wroot = (const float*)d_in[9];
    const float* broot = (const float*)d_in[10];
    const float* Wnbr  = (const float*)d_in[11];
    const float* Wedge = (const float*)d_in[12];
    const float* gamma = (const float*)d_in[13];
    const float* beta  = (const float*)d_in[14];
    const float* W1    = (const float*)d_in[15];
    const float* b1    = (const float*)d_in[16];
    const float* W2    = (const float*)d_in[17];
    const float* b2    = (const float*)d_in[18];
    float* out = (float*)d_out;

    char* p = (char*)d_ws;
    auto alloc = [&](size_t bytes) -> char* {
        char* r = p; p += (bytes + 255) & ~(size_t)255; return r;
    };
    float* h      = (float*)alloc((size_t)NN * 128 * 4);
    float* aggb   = (float*)alloc((size_t)NN * 128 * 4);   // also h1 (in-place)
    float* ea     = (float*)alloc((size_t)NN * 16 * 4);
    int*   cnt    = (int*)alloc((size_t)NN * 4);
    int*   offs   = (int*)alloc((size_t)NN * 4);
    int*   fil    = (int*)alloc((size_t)NN * 4);
    int*   elist  = (int*)alloc((size_t)EE * 4);
    int*   bsum   = (int*)alloc(128 * 4);
    int*   bpre   = (int*)alloc(128 * 4);
    float* stats  = (float*)alloc(256 * 4);
    float* ssb    = (float*)alloc(256 * 4);
    float* subsum = (float*)alloc((size_t)TOTSUB * 128 * 4);
    int*   scnt   = (int*)alloc((size_t)TOTSUB * 4);
    int*   soffs  = (int*)alloc((size_t)GG * 4);

    const int* srcp = eidx;
    const int* dstp = eidx + EE;

    hipMemsetAsync(cnt, 0, (size_t)NN * 4, stream);
    hipMemsetAsync(fil, 0, (size_t)NN * 4, stream);
    hipMemsetAsync(ea, 0, (size_t)NN * 16 * 4, stream);
    hipMemsetAsync(subsum, 0, (size_t)TOTSUB * 128 * 4, stream);
    hipMemsetAsync(scnt, 0, (size_t)TOTSUB * 4, stream);

    k_soffs<<<1, 1, 0, stream>>>(nsub, soffs);
    k_hist<<<(EE + 255) / 256, 256, 0, stream>>>(dstp, cnt);
    const int NB = (NN + 1023) / 1024;
    k_scan1<<<NB, 256, 0, stream>>>(cnt, bsum);
    k_scan2<<<1, 1, 0, stream>>>(bsum, bpre, NB);
    k_scan3<<<NB, 256, 0, stream>>>(cnt, bpre, offs);
    k_fill<<<(EE + 255) / 256, 256, 0, stream>>>(srcp, dstp, offs, fil, elist);
    k_ea<<<(EE + 255) / 256, 256, 0, stream>>>(dstp, eattr, ea);

    const int GB = (NN + 63) / 64;
    // encoder: h = x @ enc_W + enc_b (no BN stats)
    k_gemm<<<GB, 256, 0, stream>>>(x, nullptr, nullptr, encW, nullptr, nullptr, encB,
                                   h, 1, nullptr);

    for (int i = 0; i < LL; ++i) {
        k_agg<<<(NN * 64 + 255) / 256, 256, 0, stream>>>(h, offs, cnt, elist, aggb);
        hipMemsetAsync(stats, 0, 256 * 4, stream);
        k_gemm<<<GB, 256, 0, stream>>>(h, aggb, ea,
                                       Wroot + (size_t)i * 128 * 128,
                                       Wnbr + (size_t)i * 128 * 128,
                                       Wedge + (size_t)i * 16 * 128,
                                       broot + (size_t)i * 128, aggb, 3, stats);
        k_bnfin<<<1, 128, 0, stream>>>(stats, gamma + (size_t)i * 128,
                                       beta + (size_t)i * 128, ssb);
        if (i < LL - 1)
            k_bnrelu<<<2048, 256, 0, stream>>>(aggb, ssb, h);
        // last layer: BN+ReLU fused into k_pool (reads aggb directly)
    }

    k_pool<<<(NN * 64 + 255) / 256, 256, 0, stream>>>(aggb, ssb, batch, subb, soffs,
                                                      subsum, scnt);
    k_final<<<GG, 256, 0, stream>>>(subsum, scnt, soffs, W1, b1, W2, b2, out);
}

// Round 11
// 1128.090 us; speedup vs baseline: 1.4775x; 1.4775x over previous
//
#include <hip/hip_runtime.h>

#define NN 100000
#define EE 600000
#define GG 512
#define SSUB 8
#define LL 3
#define EMB 128
#define EDIM 16
#define NTASK 10
#define TOTSUB 4096
#define BN_EPS 1e-5f

// ---------------- CSR build ----------------
__global__ void k_hist(const int* __restrict__ dstp, int* __restrict__ cnt) {
    int e = blockIdx.x * 256 + threadIdx.x;
    if (e < EE) atomicAdd(&cnt[dstp[e]], 1);
}

__global__ void k_scan1(const int* __restrict__ cnt, int* __restrict__ bsum) {
    __shared__ int sd[256];
    int t = threadIdx.x, b = blockIdx.x;
    int n0 = b * 1024 + t * 4;
    int s = 0;
    for (int i = 0; i < 4; ++i) { int n = n0 + i; if (n < NN) s += cnt[n]; }
    sd[t] = s; __syncthreads();
    for (int o = 128; o > 0; o >>= 1) { if (t < o) sd[t] += sd[t + o]; __syncthreads(); }
    if (t == 0) bsum[b] = sd[0];
}

__global__ void k_scan2(const int* __restrict__ bsum, int* __restrict__ bpre, int nb) {
    int run = 0;
    for (int i = 0; i < nb; ++i) { bpre[i] = run; run += bsum[i]; }
}

__global__ void k_scan3(const int* __restrict__ cnt, const int* __restrict__ bpre,
                        int* __restrict__ offs) {
    __shared__ int sd[256];
    int t = threadIdx.x, b = blockIdx.x;
    int n0 = b * 1024 + t * 4;
    int v[4]; int ts = 0;
    for (int i = 0; i < 4; ++i) { int n = n0 + i; v[i] = (n < NN) ? cnt[n] : 0; ts += v[i]; }
    sd[t] = ts; __syncthreads();
    int sum = ts;
    for (int o = 1; o < 256; o <<= 1) {
        int x = (t >= o) ? sd[t - o] : 0;
        __syncthreads();
        sum += x; sd[t] = sum;
        __syncthreads();
    }
    int run = sum - ts + bpre[b];
    for (int i = 0; i < 4; ++i) { int n = n0 + i; if (n < NN) offs[n] = run; run += v[i]; }
}

__global__ void k_fill(const int* __restrict__ srcp, const int* __restrict__ dstp,
                       const int* __restrict__ offs, int* __restrict__ fil,
                       int* __restrict__ elist, int* __restrict__ eidlist) {
    int e = blockIdx.x * 256 + threadIdx.x;
    if (e >= EE) return;
    int d = dstp[e];
    int p = atomicAdd(&fil[d], 1);
    int slot = offs[d] + p;
    elist[slot] = srcp[e];
    eidlist[slot] = e;
}

// ---------------- graph boundaries (batch is sorted) ----------------
__global__ void k_gb(const int* __restrict__ batch, int* __restrict__ gstart,
                     int* __restrict__ gend) {
    int i = blockIdx.x * 256 + threadIdx.x;
    if (i >= NN) return;
    int b = batch[i];
    if (i == 0 || batch[i - 1] != b) gstart[b] = i;
    if (i == NN - 1 || batch[i + 1] != b) gend[b] = i + 1;
}

// ---------------- edge_attr aggregate via CSR gather (no atomics) ----------------
// wave per node; lanes 0-15 = dims (64B coalesced per edge), 4 edges in flight.
__global__ __launch_bounds__(256) void k_eag(const float* __restrict__ eattr,
                                             const int* __restrict__ offs,
                                             const int* __restrict__ cnt,
                                             const int* __restrict__ eidlist,
                                             float* __restrict__ ea) {
    int w = (blockIdx.x * 256 + threadIdx.x) >> 6;
    int lane = threadIdx.x & 63;
    if (w >= NN) return;
    int off = offs[w], deg = cnt[w];
    int slot = lane >> 4, dim = lane & 15;
    float a = 0.f;
    for (int j = slot; j < deg; j += 4) {
        int e = eidlist[off + j];
        a += eattr[(size_t)e * 16 + dim];
    }
    a += __shfl_xor(a, 16);
    a += __shfl_xor(a, 32);
    if (slot == 0) ea[(size_t)w * 16 + dim] = a;
}

// ---------------- per-layer neighbor gather-sum (no atomics) ----------------
__global__ __launch_bounds__(256) void k_agg(const float* __restrict__ h,
                                             const int* __restrict__ offs,
                                             const int* __restrict__ cnt,
                                             const int* __restrict__ elist,
                                             float* __restrict__ agg) {
    int w = (blockIdx.x * 256 + threadIdx.x) >> 6;   // wave per node
    int lane = threadIdx.x & 63;
    if (w >= NN) return;
    int off = offs[w], deg = cnt[w];
    float ax = 0.f, ay = 0.f;
    for (int j = 0; j < deg; ++j) {
        int s = elist[off + j];
        float2 v = *(const float2*)&h[(size_t)s * 128 + lane * 2];
        ax += v.x; ay += v.y;
    }
    float2 o; o.x = ax; o.y = ay;
    *(float2*)&agg[(size_t)w * 128 + lane * 2] = o;
}

// ---------------- fused GEMM: out = b + in0@W0 [+ in1@W1 + in2@W2] ----------------
// 64 rows x 128 cols per block, K chunks of 8 staged in LDS. f32 VALU.
// Optionally accumulates per-column sum/sumsq of the output into statsp[256].
__global__ __launch_bounds__(256) void k_gemm(const float* __restrict__ in0,
                                              const float* __restrict__ in1,
                                              const float* __restrict__ in2,
                                              const float* __restrict__ W0,
                                              const float* __restrict__ W1p,
                                              const float* __restrict__ W2p,
                                              const float* __restrict__ bias,
                                              float* __restrict__ outp, int nseg,
                                              float* __restrict__ statsp) {
    __shared__ union {
        struct { float W[8][128]; float In[64][9]; } s;   // staging (6.3 KB)
        struct { float sum[16][128]; float sq[16][128]; } r; // epilogue reduce (16 KB)
    } sm;
    int t = threadIdx.x;
    int tc = t & 15, tr = t >> 4;
    int rowBase = blockIdx.x * 64;
    float acc[4][8];
#pragma unroll
    for (int i = 0; i < 4; ++i)
#pragma unroll
        for (int j = 0; j < 8; ++j) acc[i][j] = 0.f;

    for (int seg = 0; seg < nseg; ++seg) {
        const float* in = (seg == 0) ? in0 : (seg == 1) ? in1 : in2;
        const float* W  = (seg == 0) ? W0  : (seg == 1) ? W1p : W2p;
        int K = (seg == 2) ? 16 : 128;
        for (int kb = 0; kb < K; kb += 8) {
            {   // stage W chunk: 8x128
                int fo = t * 4, kk = fo >> 7, cc = fo & 127;
                *(float4*)&sm.s.W[kk][cc] = *(const float4*)&W[(size_t)(kb + kk) * 128 + cc];
            }
            {   // stage input chunk: 64 rows x 8 k
                int rr = t >> 2, part = (t & 3) * 2;
                int gr = rowBase + rr;
                float2 v; v.x = 0.f; v.y = 0.f;
                if (gr < NN) v = *(const float2*)&in[(size_t)gr * K + kb + part];
                sm.s.In[rr][part] = v.x; sm.s.In[rr][part + 1] = v.y;
            }
            __syncthreads();
#pragma unroll
            for (int kk = 0; kk < 8; ++kk) {
                float4 wa = *(const float4*)&sm.s.W[kk][tc * 4];
                float4 wb = *(const float4*)&sm.s.W[kk][64 + tc * 4];
#pragma unroll
                for (int i = 0; i < 4; ++i) {
                    float a = sm.s.In[tr * 4 + i][kk];
                    acc[i][0] += a * wa.x; acc[i][1] += a * wa.y;
                    acc[i][2] += a * wa.z; acc[i][3] += a * wa.w;
                    acc[i][4] += a * wb.x; acc[i][5] += a * wb.y;
                    acc[i][6] += a * wb.z; acc[i][7] += a * wb.w;
                }
            }
            __syncthreads();
        }
    }
    float4 ba = *(const float4*)&bias[tc * 4];
    float4 bb = *(const float4*)&bias[64 + tc * 4];
    float ls[8], lq[8];
#pragma unroll
    for (int j = 0; j < 8; ++j) { ls[j] = 0.f; lq[j] = 0.f; }
#pragma unroll
    for (int i = 0; i < 4; ++i) {
        int gr = rowBase + tr * 4 + i;
        if (gr >= NN) continue;
        float o[8];
        o[0] = acc[i][0] + ba.x; o[1] = acc[i][1] + ba.y;
        o[2] = acc[i][2] + ba.z; o[3] = acc[i][3] + ba.w;
        o[4] = acc[i][4] + bb.x; o[5] = acc[i][5] + bb.y;
        o[6] = acc[i][6] + bb.z; o[7] = acc[i][7] + bb.w;
#pragma unroll
        for (int j = 0; j < 8; ++j) { ls[j] += o[j]; lq[j] += o[j] * o[j]; }
        float4 o1, o2;
        o1.x = o[0]; o1.y = o[1]; o1.z = o[2]; o1.w = o[3];
        o2.x = o[4]; o2.y = o[5]; o2.z = o[6]; o2.w = o[7];
        *(float4*)&outp[(size_t)gr * 128 + tc * 4] = o1;
        *(float4*)&outp[(size_t)gr * 128 + 64 + tc * 4] = o2;
    }
    if (statsp) {
#pragma unroll
        for (int j = 0; j < 8; ++j) {
            int col = (j < 4) ? tc * 4 + j : 64 + tc * 4 + (j - 4);
            sm.r.sum[tr][col] = ls[j];
            sm.r.sq[tr][col] = lq[j];
        }
        __syncthreads();
        if (t < 128) {
            float s = 0.f;
#pragma unroll
            for (int r = 0; r < 16; ++r) s += sm.r.sum[r][t];
            atomicAdd(&statsp[t], s);
        } else {
            int c = t - 128;
            float q = 0.f;
#pragma unroll
            for (int r = 0; r < 16; ++r) q += sm.r.sq[r][c];
            atomicAdd(&statsp[128 + c], q);
        }
    }
}

// ---------------- BatchNorm ----------------
__global__ void k_bnfin(const float* __restrict__ stats, const float* __restrict__ gamma,
                        const float* __restrict__ beta, float* __restrict__ ss) {
    int c = threadIdx.x;
    float mu = stats[c] * (1.0f / (float)NN);
    float var = stats[128 + c] * (1.0f / (float)NN) - mu * mu;
    float sc = gamma[c] * rsqrtf(var + BN_EPS);
    ss[c] = sc;
    ss[128 + c] = beta[c] - mu * sc;
}

__global__ void k_bnrelu(const float* __restrict__ h1, const float* __restrict__ ss,
                         float* __restrict__ h) {
    int total = NN * 32;  // float4 count
    for (int i = blockIdx.x * blockDim.x + threadIdx.x; i < total;
         i += gridDim.x * blockDim.x) {
        float4 v = ((const float4*)h1)[i];
        int c = (i * 4) & 127;
        float4 sc = *(const float4*)&ss[c];
        float4 sh = *(const float4*)&ss[128 + c];
        v.x = fmaxf(fmaf(v.x, sc.x, sh.x), 0.f);
        v.y = fmaxf(fmaf(v.y, sc.y, sh.y), 0.f);
        v.z = fmaxf(fmaf(v.z, sc.z, sh.z), 0.f);
        v.w = fmaxf(fmaf(v.w, sc.w, sh.w), 0.f);
        ((float4*)h)[i] = v;
    }
}

// ---- fused last-layer BN+ReLU + subgraph/graph mean-pool + final MLP ----
// One block per graph (batch sorted -> contiguous node range [gstart,gend)).
// Two wave-aligned half-block LDS accumulators -> zero atomics.
__global__ __launch_bounds__(256) void k_poolfinal(const float* __restrict__ h1,
                                                   const float* __restrict__ ss,
                                                   const int* __restrict__ subb,
                                                   const int* __restrict__ gstart,
                                                   const int* __restrict__ gend,
                                                   const float* __restrict__ W1,
                                                   const float* __restrict__ b1,
                                                   const float* __restrict__ W2,
                                                   const float* __restrict__ b2,
                                                   float* __restrict__ out) {
    __shared__ float acc[2][SSUB][EMB];   // 8 KB
    __shared__ int   cnt[2][SSUB];
    __shared__ float hg[EMB];
    __shared__ float mid[2 * EMB];
    int g = blockIdx.x, t = threadIdx.x;
    int half = t >> 7, dim = t & 127;
#pragma unroll
    for (int s = 0; s < SSUB; ++s) acc[half][s][dim] = 0.f;
    if (dim < SSUB) cnt[half][dim] = 0;
    __syncthreads();
    int start = gstart[g], end = gend[g];
    float sc = ss[dim], sh = ss[128 + dim];
    // halves are wave-aligned (t<128 = waves 0-1, t>=128 = waves 2-3); each half
    // processes one node per iteration -> sb uniform per half, dim distinct -> no race.
    for (int n = start + half; n < end; n += 2) {
        int sb = subb[n];
        float v = h1[(size_t)n * 128 + dim];
        v = fmaxf(fmaf(v, sc, sh), 0.f);
        acc[half][sb][dim] += v;
        if (dim == 0) cnt[half][sb] += 1;
    }
    __syncthreads();
    if (t < 128) {
        float s = 0.f;
#pragma unroll
        for (int u = 0; u < SSUB; ++u) {
            int c = cnt[0][u] + cnt[1][u]; if (c < 1) c = 1;
            s += (acc[0][u][t] + acc[1][u][t]) / (float)c;
        }
        hg[t] = s * (1.0f / (float)SSUB);
    }
    __syncthreads();
    {
        float m = b1[t];
        for (int c = 0; c < 128; ++c) m += hg[c] * W1[(size_t)c * 256 + t];
        mid[t] = fmaxf(m, 0.f);
    }
    __syncthreads();
    if (t < NTASK) {
        float o = b2[t];
        for (int j = 0; j < 256; ++j) o += mid[j] * W2[(size_t)j * 10 + t];
        out[(size_t)g * 10 + t] = o;
    }
}

extern "C" void kernel_launch(void* const* d_in, const int* in_sizes, int n_in,
                              void* d_out, int out_size, void* d_ws, size_t ws_size,
                              hipStream_t stream) {
    (void)in_sizes; (void)n_in; (void)out_size; (void)ws_size;
    const float* x     = (const float*)d_in[0];
    const int*   eidx  = (const int*)d_in[1];
    const float* eattr = (const float*)d_in[2];
    const int*   batch = (const int*)d_in[3];
    const int*   subb  = (const int*)d_in[4];
    const float* encW  = (const float*)d_in[7];
    const float* encB  = (const float*)d_in[8];
    const float* Wroot = (const float*)d_in[9];
    const float* broot = (const float*)d_in[10];
    const float* Wnbr  = (const float*)d_in[11];
    const float* Wedge = (const float*)d_in[12];
    const float* gamma = (const float*)d_in[13];
    const float* beta  = (const float*)d_in[14];
    const float* W1    = (const float*)d_in[15];
    const float* b1    = (const float*)d_in[16];
    const float* W2    = (const float*)d_in[17];
    const float* b2    = (const float*)d_in[18];
    float* out = (float*)d_out;

    char* p = (char*)d_ws;
    auto alloc = [&](size_t bytes) -> char* {
        char* r = p; p += (bytes + 255) & ~(size_t)255; return r;
    };
    float* h       = (float*)alloc((size_t)NN * 128 * 4);
    float* aggb    = (float*)alloc((size_t)NN * 128 * 4);   // also h1 (in-place)
    float* ea      = (float*)alloc((size_t)NN * 16 * 4);
    int*   cnt     = (int*)alloc((size_t)NN * 4);
    int*   offs    = (int*)alloc((size_t)NN * 4);
    int*   fil     = (int*)alloc((size_t)NN * 4);
    int*   elist   = (int*)alloc((size_t)EE * 4);
    int*   eidlist = (int*)alloc((size_t)EE * 4);
    int*   bsum    = (int*)alloc(128 * 4);
    int*   bpre    = (int*)alloc(128 * 4);
    float* stats   = (float*)alloc(256 * 4);
    float* ssb     = (float*)alloc(256 * 4);
    int*   gstart  = (int*)alloc((size_t)GG * 4);
    int*   gend    = (int*)alloc((size_t)GG * 4);

    const int* srcp = eidx;
    const int* dstp = eidx + EE;

    hipMemsetAsync(cnt, 0, (size_t)NN * 4, stream);
    hipMemsetAsync(fil, 0, (size_t)NN * 4, stream);
    hipMemsetAsync(gstart, 0, (size_t)GG * 4, stream);
    hipMemsetAsync(gend, 0, (size_t)GG * 4, stream);

    k_hist<<<(EE + 255) / 256, 256, 0, stream>>>(dstp, cnt);
    k_gb<<<(NN + 255) / 256, 256, 0, stream>>>(batch, gstart, gend);
    const int NB = (NN + 1023) / 1024;
    k_scan1<<<NB, 256, 0, stream>>>(cnt, bsum);
    k_scan2<<<1, 1, 0, stream>>>(bsum, bpre, NB);
    k_scan3<<<NB, 256, 0, stream>>>(cnt, bpre, offs);
    k_fill<<<(EE + 255) / 256, 256, 0, stream>>>(srcp, dstp, offs, fil, elist, eidlist);
    // edge_attr aggregate via CSR gather (replaces 9.6M-atomic k_ea: was 500us, 30% of total)
    k_eag<<<(NN * 64 + 255) / 256, 256, 0, stream>>>(eattr, offs, cnt, eidlist, ea);

    const int GB = (NN + 63) / 64;
    // encoder: h = x @ enc_W + enc_b (no BN stats)
    k_gemm<<<GB, 256, 0, stream>>>(x, nullptr, nullptr, encW, nullptr, nullptr, encB,
                                   h, 1, nullptr);

    for (int i = 0; i < LL; ++i) {
        k_agg<<<(NN * 64 + 255) / 256, 256, 0, stream>>>(h, offs, cnt, elist, aggb);
        hipMemsetAsync(stats, 0, 256 * 4, stream);
        k_gemm<<<GB, 256, 0, stream>>>(h, aggb, ea,
                                       Wroot + (size_t)i * 128 * 128,
                                       Wnbr + (size_t)i * 128 * 128,
                                       Wedge + (size_t)i * 16 * 128,
                                       broot + (size_t)i * 128, aggb, 3, stats);
        k_bnfin<<<1, 128, 0, stream>>>(stats, gamma + (size_t)i * 128,
                                       beta + (size_t)i * 128, ssb);
        if (i < LL - 1)
            k_bnrelu<<<2048, 256, 0, stream>>>(aggb, ssb, h);
        // last layer: BN+ReLU fused into k_poolfinal (reads aggb directly)
    }

    // fused BN+ReLU + two-level mean pool + MLP, one block/graph, no atomics
    k_poolfinal<<<GG, 256, 0, stream>>>(aggb, ssb, subb, gstart, gend,
                                        W1, b1, W2, b2, out);
}

// Round 14
// 750.764 us; speedup vs baseline: 2.2201x; 1.5026x over previous
//
#include <hip/hip_runtime.h>

#define NN 100000
#define NP 100096          // NN padded to 128-row blocks
#define EE 600000
#define GG 512
#define SSUB 8
#define LL 3
#define EMB 128
#define NTASK 10
#define BN_EPS 1e-5f
#define WF_ENC 16384       // enc Wf elems (8nt*4ks*64*8)
#define WF_LAY 36864       // layer Wf elems (8nt*9ks*64*8)

typedef __attribute__((ext_vector_type(8))) short short8;   // 8 bf16 (4 VGPR)
typedef __attribute__((ext_vector_type(4))) float f32x4;    // MFMA acc (4 VGPR)

__device__ __forceinline__ float b2f(unsigned short u) {
    return __uint_as_float((unsigned int)u << 16);
}
__device__ __forceinline__ unsigned short f2b(float f) {    // RNE f32->bf16
    unsigned int x = __float_as_uint(f);
    return (unsigned short)((x + 0x7fffu + ((x >> 16) & 1u)) >> 16);
}

// ---------------- CSR build ----------------
__global__ void k_hist(const int* __restrict__ dstp, int* __restrict__ cnt) {
    int e = blockIdx.x * 256 + threadIdx.x;
    if (e < EE) atomicAdd(&cnt[dstp[e]], 1);
}

__global__ void k_scan1(const int* __restrict__ cnt, int* __restrict__ bsum) {
    __shared__ int sd[256];
    int t = threadIdx.x, b = blockIdx.x;
    int n0 = b * 1024 + t * 4;
    int s = 0;
    for (int i = 0; i < 4; ++i) { int n = n0 + i; if (n < NN) s += cnt[n]; }
    sd[t] = s; __syncthreads();
    for (int o = 128; o > 0; o >>= 1) { if (t < o) sd[t] += sd[t + o]; __syncthreads(); }
    if (t == 0) bsum[b] = sd[0];
}

__global__ void k_scan2(const int* __restrict__ bsum, int* __restrict__ bpre, int nb) {
    int run = 0;
    for (int i = 0; i < nb; ++i) { bpre[i] = run; run += bsum[i]; }
}

__global__ void k_scan3(const int* __restrict__ cnt, const int* __restrict__ bpre,
                        int* __restrict__ offs) {
    __shared__ int sd[256];
    int t = threadIdx.x, b = blockIdx.x;
    int n0 = b * 1024 + t * 4;
    int v[4]; int ts = 0;
    for (int i = 0; i < 4; ++i) { int n = n0 + i; v[i] = (n < NN) ? cnt[n] : 0; ts += v[i]; }
    sd[t] = ts; __syncthreads();
    int sum = ts;
    for (int o = 1; o < 256; o <<= 1) {
        int x = (t >= o) ? sd[t - o] : 0;
        __syncthreads();
        sum += x; sd[t] = sum;
        __syncthreads();
    }
    int run = sum - ts + bpre[b];
    for (int i = 0; i < 4; ++i) { int n = n0 + i; if (n < NN) offs[n] = run; run += v[i]; }
}

__global__ void k_fill(const int* __restrict__ srcp, const int* __restrict__ dstp,
                       const int* __restrict__ offs, int* __restrict__ fil,
                       int* __restrict__ elist, int* __restrict__ eidlist) {
    int e = blockIdx.x * 256 + threadIdx.x;
    if (e >= EE) return;
    int d = dstp[e];
    int p = atomicAdd(&fil[d], 1);
    int slot = offs[d] + p;
    elist[slot] = srcp[e];
    eidlist[slot] = e;
}

// ---------------- graph boundaries (batch is sorted) ----------------
__global__ void k_gb(const int* __restrict__ batch, int* __restrict__ gstart,
                     int* __restrict__ gend) {
    int i = blockIdx.x * 256 + threadIdx.x;
    if (i >= NN) return;
    int b = batch[i];
    if (i == 0 || batch[i - 1] != b) gstart[b] = i;
    if (i == NN - 1 || batch[i + 1] != b) gend[b] = i + 1;
}

// ---------------- x -> bf16 ----------------
__global__ void k_cvtx(const float* __restrict__ x, unsigned short* __restrict__ xb) {
    int i = blockIdx.x * 256 + threadIdx.x;   // float4 index
    if (i >= NN * 32) return;
    float4 v = ((const float4*)x)[i];
    uint2 o;
    o.x = (unsigned int)f2b(v.x) | ((unsigned int)f2b(v.y) << 16);
    o.y = (unsigned int)f2b(v.z) | ((unsigned int)f2b(v.w) << 16);
    ((uint2*)xb)[i] = o;
}

// ---------------- weight repack: fragment-major bf16 ----------------
// Wf element u within matrix: u = ((nt*KS + ks)*64 + lane)*8 + j
// maps to W_combined[k = ks*32 + (lane>>4)*8 + j][n = nt*16 + (lane&15)]
__global__ void k_wprep(const float* __restrict__ encW, const float* __restrict__ Wroot,
                        const float* __restrict__ Wnbr, const float* __restrict__ Wedge,
                        unsigned short* __restrict__ Wf) {
    int idx = blockIdx.x * 256 + threadIdx.x;
    const int TOT = WF_ENC + LL * WF_LAY;
    if (idx >= TOT) return;
    int KS, li = 0, base, u;
    if (idx < WF_ENC) { KS = 4; base = 0; u = idx; }
    else { int r = idx - WF_ENC; li = r / WF_LAY; u = r % WF_LAY; KS = 9; base = WF_ENC + li * WF_LAY; }
    int j = u & 7, lane = (u >> 3) & 63, rest = u >> 9;
    int ks = rest % KS, nt = rest / KS;
    int k = ks * 32 + (lane >> 4) * 8 + j;
    int n = nt * 16 + (lane & 15);
    float v;
    if (KS == 4) v = encW[k * 128 + n];
    else if (k < 128) v = Wroot[li * 16384 + k * 128 + n];
    else if (k < 256) v = Wnbr[li * 16384 + (k - 128) * 128 + n];
    else if (k < 272) v = Wedge[li * 2048 + (k - 256) * 128 + n];
    else v = 0.f;
    Wf[base + u] = f2b(v);
}

// ---------------- edge_attr aggregate via CSR gather -> bf16 [NP][32] ----------------
__global__ __launch_bounds__(256) void k_eag(const float* __restrict__ eattr,
                                             const int* __restrict__ offs,
                                             const int* __restrict__ cnt,
                                             const int* __restrict__ eidlist,
                                             unsigned short* __restrict__ ea) {
    int w = (blockIdx.x * 256 + threadIdx.x) >> 6;
    int lane = threadIdx.x & 63;
    if (w >= NN) return;
    int off = offs[w], deg = cnt[w];
    int slot = lane >> 4, dim = lane & 15;
    float a = 0.f;
    for (int j = slot; j < deg; j += 4) {
        int e = eidlist[off + j];
        a += eattr[(size_t)e * 16 + dim];
    }
    a += __shfl_xor(a, 16);
    a += __shfl_xor(a, 32);
    if (slot == 0) ea[(size_t)w * 32 + dim] = f2b(a);
    else if (slot == 1) ea[(size_t)w * 32 + 16 + dim] = 0;   // zero pad k 16..31
}

// ---------------- neighbor gather-sum, bf16 in / bf16 out ----------------
__global__ __launch_bounds__(256) void k_agg(const unsigned short* __restrict__ hb,
                                             const int* __restrict__ offs,
                                             const int* __restrict__ cnt,
                                             const int* __restrict__ elist,
                                             unsigned short* __restrict__ agg) {
    int w = (blockIdx.x * 256 + threadIdx.x) >> 6;
    int lane = threadIdx.x & 63;
    if (w >= NN) return;
    int off = offs[w], deg = cnt[w];
    float ax = 0.f, ay = 0.f;
    for (int j = 0; j < deg; ++j) {
        int s = elist[off + j];
        unsigned int u = *(const unsigned int*)&hb[(size_t)s * 128 + lane * 2];
        ax += b2f((unsigned short)(u & 0xffff));
        ay += b2f((unsigned short)(u >> 16));
    }
    unsigned int o = (unsigned int)f2b(ax) | ((unsigned int)f2b(ay) << 16);
    *(unsigned int*)&agg[(size_t)w * 128 + lane * 2] = o;
}

// ---------------- MFMA GEMM: out = bias + [A0|A1|A2] @ W  (bf16 in, f32 acc) ---------
// block = 128x128 tile, 4 waves of 64x64 (4 row-strips x 4 col-tiles).
// Wf staged to LDS in fragment-major order -> lane-contiguous ds_read_b128, 0 conflicts.
// ks 0-3 -> A0 (k 0..127), 4-7 -> A1 (k 128..255), 8 -> A2 (k 256..287, zero-padded).
__global__ __launch_bounds__(256) void k_mfma(const unsigned short* __restrict__ A0,
                                              const unsigned short* __restrict__ A1,
                                              const unsigned short* __restrict__ A2,
                                              const unsigned short* __restrict__ Wf,
                                              int KS, const float* __restrict__ bias,
                                              float* __restrict__ outF,
                                              unsigned short* __restrict__ outB,
                                              float* __restrict__ statsp) {
    __shared__ short8 sB[4608];          // 72 KB (worst case KS=9)
    __shared__ float lsum[128], lsq[128];
    int t = threadIdx.x;
    int units = KS * 512;
    const short8* Wg = (const short8*)Wf;
    for (int u = t; u < units; u += 256) sB[u] = Wg[u];
    if (t < 128) lsum[t] = 0.f; else lsq[t - 128] = 0.f;
    __syncthreads();

    int lane = t & 63, wi = t >> 6;
    int wr = wi >> 1, wc = wi & 1;
    int rb = blockIdx.x * 128 + wr * 64;
    int q = lane >> 4, m = lane & 15;

    f32x4 acc[4][4];
#pragma unroll
    for (int ai = 0; ai < 4; ++ai)
#pragma unroll
        for (int bi = 0; bi < 4; ++bi) acc[ai][bi] = {0.f, 0.f, 0.f, 0.f};

    for (int ks = 0; ks < KS; ++ks) {
        const unsigned short* Ap; int kof, astr;
        if (ks < 4)      { Ap = A0; kof = ks * 32;       astr = 128; }
        else if (ks < 8) { Ap = A1; kof = (ks - 4) * 32; astr = 128; }
        else             { Ap = A2; kof = 0;             astr = 32; }
        short8 a[4];
#pragma unroll
        for (int rs = 0; rs < 4; ++rs) {
            int row = rb + rs * 16 + m;
            a[rs] = *(const short8*)&Ap[(size_t)row * astr + kof + q * 8];
        }
#pragma unroll
        for (int ct = 0; ct < 4; ++ct) {
            short8 b = sB[((wc * 4 + ct) * KS + ks) * 64 + lane];
#pragma unroll
            for (int rs = 0; rs < 4; ++rs)
                acc[rs][ct] = __builtin_amdgcn_mfma_f32_16x16x32_bf16(a[rs], b, acc[rs][ct], 0, 0, 0);
        }
    }

    // epilogue: bias, store (row-guarded), fused BN stats
    float scol[4] = {0.f, 0.f, 0.f, 0.f}, qcol[4] = {0.f, 0.f, 0.f, 0.f};
#pragma unroll
    for (int rs = 0; rs < 4; ++rs) {
#pragma unroll
        for (int reg = 0; reg < 4; ++reg) {
            int row = rb + rs * 16 + q * 4 + reg;          // C/D: row=(lane>>4)*4+reg
            bool ok = row < NN;
#pragma unroll
            for (int ct = 0; ct < 4; ++ct) {
                int col = wc * 64 + ct * 16 + m;           // C/D: col=lane&15
                float v = acc[rs][ct][reg] + bias[col];
                if (ok) {
                    if (outF) outF[(size_t)row * 128 + col] = v;
                    else      outB[(size_t)row * 128 + col] = f2b(v);
                    scol[ct] += v; qcol[ct] += v * v;
                }
            }
        }
    }
    if (statsp) {
#pragma unroll
        for (int ct = 0; ct < 4; ++ct) {
            float s = scol[ct], qq = qcol[ct];
            s += __shfl_xor(s, 16);  s += __shfl_xor(s, 32);
            qq += __shfl_xor(qq, 16); qq += __shfl_xor(qq, 32);
            if (lane < 16) {
                atomicAdd(&lsum[wc * 64 + ct * 16 + lane], s);
                atomicAdd(&lsq[wc * 64 + ct * 16 + lane], qq);
            }
        }
        __syncthreads();
        if (t < 128) atomicAdd(&statsp[t], lsum[t]);
        else atomicAdd(&statsp[128 + (t - 128)], lsq[t - 128]);
    }
}

// ---------------- BatchNorm ----------------
__global__ void k_bnfin(const float* __restrict__ stats, const float* __restrict__ gamma,
                        const float* __restrict__ beta, float* __restrict__ ss) {
    int c = threadIdx.x;
    float mu = stats[c] * (1.0f / (float)NN);
    float var = stats[128 + c] * (1.0f / (float)NN) - mu * mu;
    float sc = gamma[c] * rsqrtf(var + BN_EPS);
    ss[c] = sc;
    ss[128 + c] = beta[c] - mu * sc;
}

__global__ void k_bnrelu(const float* __restrict__ h1, const float* __restrict__ ss,
                         unsigned short* __restrict__ hb) {
    int i = blockIdx.x * blockDim.x + threadIdx.x;  // float4 index
    for (; i < NN * 32; i += gridDim.x * blockDim.x) {
        float4 v = ((const float4*)h1)[i];
        int c = (i * 4) & 127;
        float4 sc = *(const float4*)&ss[c];
        float4 sh = *(const float4*)&ss[128 + c];
        v.x = fmaxf(fmaf(v.x, sc.x, sh.x), 0.f);
        v.y = fmaxf(fmaf(v.y, sc.y, sh.y), 0.f);
        v.z = fmaxf(fmaf(v.z, sc.z, sh.z), 0.f);
        v.w = fmaxf(fmaf(v.w, sc.w, sh.w), 0.f);
        uint2 o;
        o.x = (unsigned int)f2b(v.x) | ((unsigned int)f2b(v.y) << 16);
        o.y = (unsigned int)f2b(v.z) | ((unsigned int)f2b(v.w) << 16);
        ((uint2*)hb)[i] = o;
    }
}

// ---- fused last-layer BN+ReLU + two-level mean pool + final MLP (f32 h1) ----
__global__ __launch_bounds__(256) void k_poolfinal(const float* __restrict__ h1,
                                                   const float* __restrict__ ss,
                                                   const int* __restrict__ subb,
                                                   const int* __restrict__ gstart,
                                                   const int* __restrict__ gend,
                                                   const float* __restrict__ W1,
                                                   const float* __restrict__ b1,
                                                   const float* __restrict__ W2,
                                                   const float* __restrict__ b2,
                                                   float* __restrict__ out) {
    __shared__ float acc[2][SSUB][EMB];
    __shared__ int   cnt[2][SSUB];
    __shared__ float hg[EMB];
    __shared__ float mid[2 * EMB];
    int g = blockIdx.x, t = threadIdx.x;
    int half = t >> 7, dim = t & 127;
#pragma unroll
    for (int s = 0; s < SSUB; ++s) acc[half][s][dim] = 0.f;
    if (dim < SSUB) cnt[half][dim] = 0;
    __syncthreads();
    int start = gstart[g], end = gend[g];
    float sc = ss[dim], sh = ss[128 + dim];
    for (int n = start + half; n < end; n += 2) {
        int sb = subb[n];
        float v = h1[(size_t)n * 128 + dim];
        v = fmaxf(fmaf(v, sc, sh), 0.f);
        acc[half][sb][dim] += v;
        if (dim == 0) cnt[half][sb] += 1;
    }
    __syncthreads();
    if (t < 128) {
        float s = 0.f;
#pragma unroll
        for (int u = 0; u < SSUB; ++u) {
            int c = cnt[0][u] + cnt[1][u]; if (c < 1) c = 1;
            s += (acc[0][u][t] + acc[1][u][t]) / (float)c;
        }
        hg[t] = s * (1.0f / (float)SSUB);
    }
    __syncthreads();
    {
        float m = b1[t];
        for (int c = 0; c < 128; ++c) m += hg[c] * W1[(size_t)c * 256 + t];
        mid[t] = fmaxf(m, 0.f);
    }
    __syncthreads();
    if (t < NTASK) {
        float o = b2[t];
        for (int j = 0; j < 256; ++j) o += mid[j] * W2[(size_t)j * 10 + t];
        out[(size_t)g * 10 + t] = o;
    }
}

extern "C" void kernel_launch(void* const* d_in, const int* in_sizes, int n_in,
                              void* d_out, int out_size, void* d_ws, size_t ws_size,
                              hipStream_t stream) {
    (void)in_sizes; (void)n_in; (void)out_size; (void)ws_size;
    const float* x     = (const float*)d_in[0];
    const int*   eidx  = (const int*)d_in[1];
    const float* eattr = (const float*)d_in[2];
    const int*   batch = (const int*)d_in[3];
    const int*   subb  = (const int*)d_in[4];
    const float* encW  = (const float*)d_in[7];
    const float* encB  = (const float*)d_in[8];
    const float* Wroot = (const float*)d_in[9];
    const float* broot = (const float*)d_in[10];
    const float* Wnbr  = (const float*)d_in[11];
    const float* Wedge = (const float*)d_in[12];
    const float* gamma = (const float*)d_in[13];
    const float* beta  = (const float*)d_in[14];
    const float* W1    = (const float*)d_in[15];
    const float* b1    = (const float*)d_in[16];
    const float* W2    = (const float*)d_in[17];
    const float* b2    = (const float*)d_in[18];
    float* out = (float*)d_out;

    char* p = (char*)d_ws;
    auto alloc = [&](size_t bytes) -> char* {
        char* r = p; p += (bytes + 255) & ~(size_t)255; return r;
    };
    float*          h1     = (float*)alloc((size_t)NN * 128 * 4);  // f32 pre-BN output
    unsigned short* xb     = (unsigned short*)h1;                  // aliased: xb dead before h1 written
    unsigned short* hb     = (unsigned short*)alloc((size_t)NP * 128 * 2);
    unsigned short* aggb   = (unsigned short*)alloc((size_t)NP * 128 * 2);
    unsigned short* eap    = (unsigned short*)alloc((size_t)NP * 32 * 2);
    unsigned short* Wf     = (unsigned short*)alloc((size_t)(WF_ENC + LL * WF_LAY) * 2);
    int*   cnt     = (int*)alloc((size_t)NN * 4);
    int*   offs    = (int*)alloc((size_t)NN * 4);
    int*   fil     = (int*)alloc((size_t)NN * 4);
    int*   elist   = (int*)alloc((size_t)EE * 4);
    int*   eidlist = (int*)alloc((size_t)EE * 4);
    int*   bsum    = (int*)alloc(128 * 4);
    int*   bpre    = (int*)alloc(128 * 4);
    float* stats   = (float*)alloc(256 * 4);
    float* ssb     = (float*)alloc(256 * 4);
    int*   gstart  = (int*)alloc((size_t)GG * 4);
    int*   gend    = (int*)alloc((size_t)GG * 4);

    const int* srcp = eidx;
    const int* dstp = eidx + EE;

    hipMemsetAsync(cnt, 0, (size_t)NN * 4, stream);
    hipMemsetAsync(fil, 0, (size_t)NN * 4, stream);
    hipMemsetAsync(gstart, 0, (size_t)GG * 4, stream);
    hipMemsetAsync(gend, 0, (size_t)GG * 4, stream);

    k_hist<<<(EE + 255) / 256, 256, 0, stream>>>(dstp, cnt);
    k_gb<<<(NN + 255) / 256, 256, 0, stream>>>(batch, gstart, gend);
    k_cvtx<<<(NN * 32 + 255) / 256, 256, 0, stream>>>(x, xb);
    k_wprep<<<(WF_ENC + LL * WF_LAY + 255) / 256, 256, 0, stream>>>(encW, Wroot, Wnbr, Wedge, Wf);
    const int NB = (NN + 1023) / 1024;
    k_scan1<<<NB, 256, 0, stream>>>(cnt, bsum);
    k_scan2<<<1, 1, 0, stream>>>(bsum, bpre, NB);
    k_scan3<<<NB, 256, 0, stream>>>(cnt, bpre, offs);
    k_fill<<<(EE + 255) / 256, 256, 0, stream>>>(srcp, dstp, offs, fil, elist, eidlist);
    k_eag<<<(NN * 64 + 255) / 256, 256, 0, stream>>>(eattr, offs, cnt, eidlist, eap);

    const int GB2 = (NN + 127) / 128;   // 782 blocks, 128-row tiles
    // encoder: hb = bf16(x @ encW + encB)
    k_mfma<<<GB2, 256, 0, stream>>>(xb, nullptr, nullptr, Wf, 4, encB,
                                    nullptr, hb, nullptr);

    for (int i = 0; i < LL; ++i) {
        k_agg<<<(NN * 64 + 255) / 256, 256, 0, stream>>>(hb, offs, cnt, elist, aggb);
        hipMemsetAsync(stats, 0, 256 * 4, stream);
        k_mfma<<<GB2, 256, 0, stream>>>(hb, aggb, eap,
                                        Wf + WF_ENC + (size_t)i * WF_LAY, 9,
                                        broot + (size_t)i * 128,
                                        h1, nullptr, stats);
        k_bnfin<<<1, 128, 0, stream>>>(stats, gamma + (size_t)i * 128,
                                       beta + (size_t)i * 128, ssb);
        if (i < LL - 1)
            k_bnrelu<<<2048, 256, 0, stream>>>(h1, ssb, hb);
        // last layer: BN+ReLU fused into k_poolfinal (reads f32 h1)
    }

    k_poolfinal<<<GG, 256, 0, stream>>>(h1, ssb, subb, gstart, gend,
                                        W1, b1, W2, b2, out);
}